// Round 2
// baseline (1231.774 us; speedup 1.0000x reference)
//
#include <hip/hip_runtime.h>

#define NN 50000
#define NE 800000
#define RR 8
#define BB 8
#define EPSV 1e-5f

// ---------------- utility: zero fill ----------------
__global__ void zero_f32(float* __restrict__ p, long n) {
    long i = (long)blockIdx.x * blockDim.x + threadIdx.x;
    long stride = (long)gridDim.x * blockDim.x;
    for (; i < n; i += stride) p[i] = 0.f;
}

// ---------------- build Wfull[(R*64 + 64) x O] ----------------
// rows r*64+i : sum_b comp[r,b] * bases[b,i,o];  rows 512+i : root[i,o]
__global__ void build_w(const float* __restrict__ comp, const float* __restrict__ bases,
                        const float* __restrict__ root, float* __restrict__ Wfull,
                        int outDim) {
    int idx = blockIdx.x * blockDim.x + threadIdx.x;
    int tot = (RR * 64 + 64) * outDim;
    if (idx >= tot) return;
    int o = idx % outDim;
    int row = idx / outDim;
    if (row < RR * 64) {
        int r = row >> 6, i = row & 63;
        float s = 0.f;
#pragma unroll
        for (int b = 0; b < BB; ++b)
            s += comp[r * BB + b] * bases[(b * 64 + i) * outDim + o];
        Wfull[idx] = s;
    } else {
        int i = row - RR * 64;
        Wfull[idx] = root[i * outDim + o];
    }
}

// ---------------- count edges per (dst, relation) — graph-static, done once ----------------
__global__ void edge_count(const int* __restrict__ ei, const int* __restrict__ et,
                           float* __restrict__ cnt) {
    int i = blockIdx.x * blockDim.x + threadIdx.x;
    int stride = gridDim.x * blockDim.x;
    for (int e = i; e < NE; e += stride) {
        int d = ei[NE + e];
        int r = et[e];
        atomicAdd(&cnt[(size_t)d * RR + r], 1.0f);
    }
}

// ---------------- edge scatter: acc[dst,r,:] += x[src,:] ----------------
__global__ void edge_scatter(const int* __restrict__ ei, const int* __restrict__ et,
                             const float* __restrict__ x, float* __restrict__ acc) {
    int wave = (int)((blockIdx.x * blockDim.x + threadIdx.x) >> 6);
    int lane = threadIdx.x & 63;
    int nwaves = (gridDim.x * blockDim.x) >> 6;
    for (int e = wave; e < NE; e += nwaves) {
        int s = ei[e];
        int d = ei[NE + e];
        int r = et[e];
        float v = x[(size_t)s * 64 + lane];
        atomicAdd(&acc[((size_t)d * RR + r) * 64 + lane], v);
    }
}

// ---------------- dense: out[n,o] = [acc[n,:,:]/cnt ++ xin[n,:]] . Wfull[:,o] + bias ----------------
template <int O, bool RELU>
__global__ void conv_dense(const float* __restrict__ acc, const float* __restrict__ cnt,
                           const float* __restrict__ xin, const float* __restrict__ W,
                           const float* __restrict__ bias, float* __restrict__ out) {
    constexpr int NPB = 256 / O;  // nodes per block
    __shared__ float vals[NPB][576];
    int n0 = blockIdx.x * NPB;
    for (int k = threadIdx.x; k < NPB * 576; k += 256) {
        int g = k / 576, kk = k - g * 576;
        int n = n0 + g;
        float v;
        if (kk < 512) {
            int r = kk >> 6;
            float c = cnt[(size_t)n * RR + r];
            v = acc[((size_t)n * RR + r) * 64 + (kk & 63)] / fmaxf(c, 1.0f);
        } else {
            v = xin[(size_t)n * 64 + (kk - 512)];
        }
        vals[g][kk] = v;
    }
    __syncthreads();
    int g = threadIdx.x / O, o = threadIdx.x % O;
    int n = n0 + g;
    float sum = bias[o];
#pragma unroll 8
    for (int k = 0; k < 576; ++k)
        sum = fmaf(vals[g][k], W[k * O + o], sum);
    if (RELU) sum = fmaxf(sum, 0.f);
    out[(size_t)n * O + o] = sum;
}

// ---------------- batchnorm stats: stats[c]=sum, stats[64+c]=sumsq ----------------
__global__ void bn_stats(const float* __restrict__ y, float* __restrict__ stats) {
    int c = threadIdx.x & 63;
    int rg = threadIdx.x >> 6;  // 0..3
    float s = 0.f, q = 0.f;
    for (int n = blockIdx.x * 4 + rg; n < NN; n += gridDim.x * 4) {
        float v = y[(size_t)n * 64 + c];
        s += v;
        q += v * v;
    }
    __shared__ float ls[4][64], lq[4][64];
    ls[rg][c] = s;
    lq[rg][c] = q;
    __syncthreads();
    if (rg == 0) {
        s = ls[0][c] + ls[1][c] + ls[2][c] + ls[3][c];
        q = lq[0][c] + lq[1][c] + lq[2][c] + lq[3][c];
        atomicAdd(&stats[c], s);
        atomicAdd(&stats[64 + c], q);
    }
}

__global__ void bn_finalize(const float* __restrict__ stats, const float* __restrict__ gamma,
                            const float* __restrict__ beta, float* __restrict__ sc) {
    int c = threadIdx.x;
    if (c < 64) {
        float mu = stats[c] / (float)NN;
        float var = stats[64 + c] / (float)NN - mu * mu;
        float scale = gamma[c] * rsqrtf(var + EPSV);
        sc[c] = scale;
        sc[64 + c] = beta[c] - mu * scale;
    }
}

// h = y*scale + shift (+ res)
__global__ void bn_apply(const float* __restrict__ y, const float* __restrict__ sc,
                         const float* __restrict__ res, float* __restrict__ h) {
    long tot = (long)NN * 64;
    long stride = (long)gridDim.x * blockDim.x;
    for (long i = (long)blockIdx.x * blockDim.x + threadIdx.x; i < tot; i += stride) {
        int c = (int)(i & 63);
        float v = y[i] * sc[c] + sc[64 + c];
        if (res) v += res[i];
        h[i] = v;
    }
}

extern "C" void kernel_launch(void* const* d_in, const int* in_sizes, int n_in,
                              void* d_out, int out_size, void* d_ws, size_t ws_size,
                              hipStream_t stream) {
    const float* x      = (const float*)d_in[0];
    const int*   ei     = (const int*)d_in[1];
    const int*   et     = (const int*)d_in[2];
    const float* comp1  = (const float*)d_in[3];
    const float* bases1 = (const float*)d_in[4];
    const float* root1  = (const float*)d_in[5];
    const float* bias1  = (const float*)d_in[6];
    const float* comp2  = (const float*)d_in[7];
    const float* bases2 = (const float*)d_in[8];
    const float* root2  = (const float*)d_in[9];
    const float* bias2  = (const float*)d_in[10];
    const float* comp3  = (const float*)d_in[11];
    const float* bases3 = (const float*)d_in[12];
    const float* root3  = (const float*)d_in[13];
    const float* bias3  = (const float*)d_in[14];
    const float* gamma1 = (const float*)d_in[15];
    const float* beta1  = (const float*)d_in[16];
    const float* gamma2 = (const float*)d_in[17];
    const float* beta2  = (const float*)d_in[18];
    float* out = (float*)d_out;

    float* ws = (float*)d_ws;
    size_t off = 0;
    float* W1 = ws + off; off += 576 * 64;
    float* W2 = ws + off; off += 576 * 64;
    float* W3 = ws + off; off += 576 * 32;
    float* stats = ws + off; off += 128;
    float* sc = ws + off; off += 128;
    float* cnt = ws + off; off += (size_t)NN * RR;          // 400000
    float* acc = ws + off; off += (size_t)NN * RR * 64;     // 25.6M
    float* y  = ws + off; off += (size_t)NN * 64;
    float* h1 = ws + off; off += (size_t)NN * 64;
    float* h  = ws + off; off += (size_t)NN * 64;

    // weights + per-(dst,rel) counts (graph-static: compute once)
    build_w<<<dim3((576 * 64 + 255) / 256), dim3(256), 0, stream>>>(comp1, bases1, root1, W1, 64);
    build_w<<<dim3((576 * 64 + 255) / 256), dim3(256), 0, stream>>>(comp2, bases2, root2, W2, 64);
    build_w<<<dim3((576 * 32 + 255) / 256), dim3(256), 0, stream>>>(comp3, bases3, root3, W3, 32);
    zero_f32<<<dim3(512), dim3(256), 0, stream>>>(cnt, (long)NN * RR);
    edge_count<<<dim3(1024), dim3(256), 0, stream>>>(ei, et, cnt);

    // ---- layer 1 ----
    zero_f32<<<dim3(2048), dim3(256), 0, stream>>>(acc, (long)NN * RR * 64);
    edge_scatter<<<dim3(2048), dim3(256), 0, stream>>>(ei, et, x, acc);
    conv_dense<64, true><<<dim3(NN / 4), dim3(256), 0, stream>>>(acc, cnt, x, W1, bias1, y);
    zero_f32<<<dim3(1), dim3(128), 0, stream>>>(stats, 128);
    bn_stats<<<dim3(256), dim3(256), 0, stream>>>(y, stats);
    bn_finalize<<<dim3(1), dim3(64), 0, stream>>>(stats, gamma1, beta1, sc);
    bn_apply<<<dim3(2048), dim3(256), 0, stream>>>(y, sc, nullptr, h1);

    // ---- layer 2 ----
    zero_f32<<<dim3(2048), dim3(256), 0, stream>>>(acc, (long)NN * RR * 64);
    edge_scatter<<<dim3(2048), dim3(256), 0, stream>>>(ei, et, h1, acc);
    conv_dense<64, true><<<dim3(NN / 4), dim3(256), 0, stream>>>(acc, cnt, h1, W2, bias2, y);
    zero_f32<<<dim3(1), dim3(128), 0, stream>>>(stats, 128);
    bn_stats<<<dim3(256), dim3(256), 0, stream>>>(y, stats);
    bn_finalize<<<dim3(1), dim3(64), 0, stream>>>(stats, gamma2, beta2, sc);
    bn_apply<<<dim3(2048), dim3(256), 0, stream>>>(y, sc, h1, h);

    // ---- layer 3 (output) ----
    zero_f32<<<dim3(2048), dim3(256), 0, stream>>>(acc, (long)NN * RR * 64);
    edge_scatter<<<dim3(2048), dim3(256), 0, stream>>>(ei, et, h, acc);
    conv_dense<32, false><<<dim3(NN / 8), dim3(256), 0, stream>>>(acc, cnt, h, W3, bias3, out);
}

// Round 4
// 699.659 us; speedup vs baseline: 1.7605x; 1.7605x over previous
//
#include <hip/hip_runtime.h>

#define NN 50000
#define NE 800000
#define RR 8
#define BB 8
#define EPSV 1e-5f
#define SCAN_B ((NN + 255) / 256)   // 196

// ---------------- utility: zero fill ----------------
__global__ void zero_f32(float* __restrict__ p, long n) {
    long i = (long)blockIdx.x * blockDim.x + threadIdx.x;
    long stride = (long)gridDim.x * blockDim.x;
    for (; i < n; i += stride) p[i] = 0.f;
}

// ---------------- build Wfull[(R*64 + 64) x O] ----------------
__global__ void build_w(const float* __restrict__ comp, const float* __restrict__ bases,
                        const float* __restrict__ root, float* __restrict__ Wfull,
                        int outDim) {
    int idx = blockIdx.x * blockDim.x + threadIdx.x;
    int tot = (RR * 64 + 64) * outDim;
    if (idx >= tot) return;
    int o = idx % outDim;
    int row = idx / outDim;
    if (row < RR * 64) {
        int r = row >> 6, i = row & 63;
        float s = 0.f;
#pragma unroll
        for (int b = 0; b < BB; ++b)
            s += comp[r * BB + b] * bases[(b * 64 + i) * outDim + o];
        Wfull[idx] = s;
    } else {
        int i = row - RR * 64;
        Wfull[idx] = root[i * outDim + o];
    }
}

// ---------------- once: per-(dst,rel) edge counts ----------------
__global__ void edge_count(const int* __restrict__ ei, const int* __restrict__ et,
                           float* __restrict__ cnt) {
    int i = blockIdx.x * blockDim.x + threadIdx.x;
    int stride = gridDim.x * blockDim.x;
    for (int e = i; e < NE; e += stride) {
        int d = ei[NE + e];
        int r = et[e];
        atomicAdd(&cnt[(size_t)d * RR + r], 1.0f);
    }
}

// ---------------- once: per-dst degree ----------------
__global__ void deg_count(const int* __restrict__ ei, int* __restrict__ deg) {
    int i = blockIdx.x * blockDim.x + threadIdx.x;
    int stride = gridDim.x * blockDim.x;
    for (int e = i; e < NE; e += stride)
        atomicAdd(&deg[ei[NE + e]], 1);
}

// ---------------- once: exclusive scan of deg -> offs (3-kernel) ----------------
__global__ void scan1(const int* __restrict__ deg, int* __restrict__ offs, int* __restrict__ bsum) {
    __shared__ int sh[256];
    int b = blockIdx.x, t = threadIdx.x;
    int i = b * 256 + t;
    int v = (i < NN) ? deg[i] : 0;
    sh[t] = v;
    __syncthreads();
    for (int s = 1; s < 256; s <<= 1) {
        int tmp = (t >= s) ? sh[t - s] : 0;
        __syncthreads();
        sh[t] += tmp;
        __syncthreads();
    }
    if (i < NN) offs[i] = sh[t] - v;   // exclusive within block
    if (t == 255) bsum[b] = sh[255];
}

__global__ void scan2(int* __restrict__ bsum, int* __restrict__ offs) {
    if (threadIdx.x == 0 && blockIdx.x == 0) {
        int run = 0;
        for (int b = 0; b < SCAN_B; ++b) { int t = bsum[b]; bsum[b] = run; run += t; }
        offs[NN] = run;  // == NE
    }
}

__global__ void scan3(int* __restrict__ offs, const int* __restrict__ bsum) {
    int b = blockIdx.x, t = threadIdx.x;
    int i = b * 256 + t;
    if (i < NN) offs[i] += bsum[b];
}

// ---------------- once: place edges into dst-sorted list (packed src<<3|r) ----------------
__global__ void place(const int* __restrict__ ei, const int* __restrict__ et,
                      const int* __restrict__ offs, int* __restrict__ fill,
                      unsigned* __restrict__ esrt) {
    int i = blockIdx.x * blockDim.x + threadIdx.x;
    int stride = gridDim.x * blockDim.x;
    for (int e = i; e < NE; e += stride) {
        int d = ei[NE + e];
        int pos = offs[d] + atomicAdd(&fill[d], 1);
        esrt[pos] = ((unsigned)ei[e] << 3) | (unsigned)et[e];
    }
}

// ---------------- per layer: gather-aggregate, normalized. acc[n][512] ----------------
__global__ __launch_bounds__(256) void aggregate(const int* __restrict__ offs,
                                                 const unsigned* __restrict__ esrt,
                                                 const float* __restrict__ cnt,
                                                 const float* __restrict__ xin,
                                                 float* __restrict__ acc) {
    int n = (blockIdx.x * 256 + threadIdx.x) >> 6;   // one wave per dst node
    int lane = threadIdx.x & 63;
    if (n >= NN) return;
    int j0 = offs[n], j1 = offs[n + 1];
    float a0 = 0.f, a1 = 0.f, a2 = 0.f, a3 = 0.f, a4 = 0.f, a5 = 0.f, a6 = 0.f, a7 = 0.f;
    for (int j = j0; j < j1; ++j) {
        unsigned u = esrt[j];                         // wave-uniform load
        int r = __builtin_amdgcn_readfirstlane((int)(u & 7u));
        int s = (int)(u >> 3);
        float v = xin[(size_t)s * 64 + lane];         // coalesced 256B row
        switch (r) {                                  // wave-uniform branch
            case 0: a0 += v; break;
            case 1: a1 += v; break;
            case 2: a2 += v; break;
            case 3: a3 += v; break;
            case 4: a4 += v; break;
            case 5: a5 += v; break;
            case 6: a6 += v; break;
            default: a7 += v; break;
        }
    }
    size_t cb = (size_t)n * RR;
    size_t base = (size_t)n * 512 + lane;
    acc[base + 0 * 64] = a0 / fmaxf(cnt[cb + 0], 1.f);
    acc[base + 1 * 64] = a1 / fmaxf(cnt[cb + 1], 1.f);
    acc[base + 2 * 64] = a2 / fmaxf(cnt[cb + 2], 1.f);
    acc[base + 3 * 64] = a3 / fmaxf(cnt[cb + 3], 1.f);
    acc[base + 4 * 64] = a4 / fmaxf(cnt[cb + 4], 1.f);
    acc[base + 5 * 64] = a5 / fmaxf(cnt[cb + 5], 1.f);
    acc[base + 6 * 64] = a6 / fmaxf(cnt[cb + 6], 1.f);
    acc[base + 7 * 64] = a7 / fmaxf(cnt[cb + 7], 1.f);
}

// ---------------- per layer: tiled SGEMM  out[MT-tile][O] = V[MT][576] x W[576][O] ----------------
// V rows: k<512 from acc (normalized), k in [512,576) from xin. XOR-swizzled LDS V tile.
template <int O, int MT, bool RELU>
__global__ __launch_bounds__(256) void rgemm(const float* __restrict__ acc,
                                             const float* __restrict__ xin,
                                             const float* __restrict__ W,
                                             const float* __restrict__ bias,
                                             float* __restrict__ out) {
    constexpr int TX = O / 4;        // threads along o
    __shared__ float Vt[MT][72];     // [node][k-pad]; col4 groups XOR-swizzled
    __shared__ float Wt[64][O + 8];
    int t = threadIdx.x;
    int tx = t % TX, ty = t / TX;    // thread tile: 4 outs x 4 nodes
    int n0 = blockIdx.x * MT;
    float a[4][4] = {};
    for (int kt = 0; kt < 9; ++kt) {
        int k0 = kt * 64;
        __syncthreads();
        // stage V tile: MT x 64 floats as float4s
        for (int idx = t; idx < MT * 16; idx += 256) {
            int nl = idx >> 4, g = idx & 15;         // g = k-group (4 floats)
            int n = n0 + nl; if (n >= NN) n = NN - 1;
            float4 p;
            if (kt < 8) p = *(const float4*)&acc[(size_t)n * 512 + k0 + g * 4];
            else        p = *(const float4*)&xin[(size_t)n * 64 + g * 4];
            int gs = g ^ ((nl >> 2) & 3);
            *(float4*)&Vt[nl][gs * 4] = p;
        }
        // stage W tile: 64 x O floats
        for (int idx = t; idx < 16 * O; idx += 256) {
            int kr = idx / TX, og = idx % TX;
            *(float4*)&Wt[kr][og * 4] = *(const float4*)&W[(size_t)(k0 + kr) * O + og * 4];
        }
        __syncthreads();
#pragma unroll
        for (int kk = 0; kk < 64; kk += 4) {
            float4 wv[4], vv[4];
#pragma unroll
            for (int d = 0; d < 4; ++d) wv[d] = *(const float4*)&Wt[kk + d][tx * 4];
#pragma unroll
            for (int i = 0; i < 4; ++i) {
                int nl = ty * 4 + i;
                int gs = (kk >> 2) ^ ((nl >> 2) & 3);
                vv[i] = *(const float4*)&Vt[nl][gs * 4];
            }
#pragma unroll
            for (int i = 0; i < 4; ++i) {
                const float* vf = (const float*)&vv[i];
#pragma unroll
                for (int d = 0; d < 4; ++d) {
                    const float* wf = (const float*)&wv[d];
                    a[i][0] = fmaf(vf[d], wf[0], a[i][0]);
                    a[i][1] = fmaf(vf[d], wf[1], a[i][1]);
                    a[i][2] = fmaf(vf[d], wf[2], a[i][2]);
                    a[i][3] = fmaf(vf[d], wf[3], a[i][3]);
                }
            }
        }
    }
    float4 bv = *(const float4*)&bias[tx * 4];
    const float* bf = (const float*)&bv;
#pragma unroll
    for (int i = 0; i < 4; ++i) {
        int n = n0 + ty * 4 + i;
        if (n < NN) {
            float4 o4;
            float* of = (float*)&o4;
#pragma unroll
            for (int j = 0; j < 4; ++j) {
                float v = a[i][j] + bf[j];
                if (RELU) v = fmaxf(v, 0.f);
                of[j] = v;
            }
            *(float4*)&out[(size_t)n * O + tx * 4] = o4;
        }
    }
}

// ---------------- batchnorm ----------------
__global__ void bn_stats(const float* __restrict__ y, float* __restrict__ stats) {
    int c = threadIdx.x & 63;
    int rg = threadIdx.x >> 6;  // 0..3
    float s = 0.f, q = 0.f;
    for (int n = blockIdx.x * 4 + rg; n < NN; n += gridDim.x * 4) {
        float v = y[(size_t)n * 64 + c];
        s += v;
        q += v * v;
    }
    __shared__ float ls[4][64], lq[4][64];
    ls[rg][c] = s;
    lq[rg][c] = q;
    __syncthreads();
    if (rg == 0) {
        s = ls[0][c] + ls[1][c] + ls[2][c] + ls[3][c];
        q = lq[0][c] + lq[1][c] + lq[2][c] + lq[3][c];
        atomicAdd(&stats[c], s);
        atomicAdd(&stats[64 + c], q);
    }
}

__global__ void bn_finalize(const float* __restrict__ stats, const float* __restrict__ gamma,
                            const float* __restrict__ beta, float* __restrict__ sc) {
    int c = threadIdx.x;
    if (c < 64) {
        float mu = stats[c] / (float)NN;
        float var = stats[64 + c] / (float)NN - mu * mu;
        float scale = gamma[c] * rsqrtf(var + EPSV);
        sc[c] = scale;
        sc[64 + c] = beta[c] - mu * scale;
    }
}

__global__ void bn_apply(const float* __restrict__ y, const float* __restrict__ sc,
                         const float* __restrict__ res, float* __restrict__ h) {
    long tot = (long)NN * 64;
    long stride = (long)gridDim.x * blockDim.x;
    for (long i = (long)blockIdx.x * blockDim.x + threadIdx.x; i < tot; i += stride) {
        int c = (int)(i & 63);
        float v = y[i] * sc[c] + sc[64 + c];
        if (res) v += res[i];
        h[i] = v;
    }
}

extern "C" void kernel_launch(void* const* d_in, const int* in_sizes, int n_in,
                              void* d_out, int out_size, void* d_ws, size_t ws_size,
                              hipStream_t stream) {
    const float* x      = (const float*)d_in[0];
    const int*   ei     = (const int*)d_in[1];
    const int*   et     = (const int*)d_in[2];
    const float* comp1  = (const float*)d_in[3];
    const float* bases1 = (const float*)d_in[4];
    const float* root1  = (const float*)d_in[5];
    const float* bias1  = (const float*)d_in[6];
    const float* comp2  = (const float*)d_in[7];
    const float* bases2 = (const float*)d_in[8];
    const float* root2  = (const float*)d_in[9];
    const float* bias2  = (const float*)d_in[10];
    const float* comp3  = (const float*)d_in[11];
    const float* bases3 = (const float*)d_in[12];
    const float* root3  = (const float*)d_in[13];
    const float* bias3  = (const float*)d_in[14];
    const float* gamma1 = (const float*)d_in[15];
    const float* beta1  = (const float*)d_in[16];
    const float* gamma2 = (const float*)d_in[17];
    const float* beta2  = (const float*)d_in[18];
    float* out = (float*)d_out;

    float* ws = (float*)d_ws;
    size_t off = 0;
    float* W1 = ws + off; off += 576 * 64;
    float* W2 = ws + off; off += 576 * 64;
    float* W3 = ws + off; off += 576 * 32;
    float* stats = ws + off; off += 128;
    float* sc = ws + off; off += 128;
    float* cnt = ws + off; off += (size_t)NN * RR;       // 400000
    float* acc = ws + off; off += (size_t)NN * 512;      // 25.6M  (normalized V, [N][512])
    float* y  = ws + off; off += (size_t)NN * 64;
    float* h1 = ws + off; off += (size_t)NN * 64;
    float* h  = ws + off; off += (size_t)NN * 64;
    int* deg  = (int*)(ws + off); off += NN;
    int* offs = (int*)(ws + off); off += NN + 4;
    int* fill = (int*)(ws + off); off += NN;
    int* bsum = (int*)(ws + off); off += 256;
    unsigned* esrt = (unsigned*)(ws + off); off += NE;

    // ---- once: weights + counts + CSR ----
    build_w<<<dim3((576 * 64 + 255) / 256), dim3(256), 0, stream>>>(comp1, bases1, root1, W1, 64);
    build_w<<<dim3((576 * 64 + 255) / 256), dim3(256), 0, stream>>>(comp2, bases2, root2, W2, 64);
    build_w<<<dim3((576 * 32 + 255) / 256), dim3(256), 0, stream>>>(comp3, bases3, root3, W3, 32);
    zero_f32<<<dim3(512), dim3(256), 0, stream>>>(cnt, (long)NN * RR);
    zero_f32<<<dim3(128), dim3(256), 0, stream>>>((float*)deg, NN);
    zero_f32<<<dim3(128), dim3(256), 0, stream>>>((float*)fill, NN);
    edge_count<<<dim3(1024), dim3(256), 0, stream>>>(ei, et, cnt);
    deg_count<<<dim3(1024), dim3(256), 0, stream>>>(ei, deg);
    scan1<<<dim3(SCAN_B), dim3(256), 0, stream>>>(deg, offs, bsum);
    scan2<<<dim3(1), dim3(64), 0, stream>>>(bsum, offs);
    scan3<<<dim3(SCAN_B), dim3(256), 0, stream>>>(offs, bsum);
    place<<<dim3(1024), dim3(256), 0, stream>>>(ei, et, offs, fill, esrt);

    // ---- layer 1 ----
    aggregate<<<dim3(NN / 4), dim3(256), 0, stream>>>(offs, esrt, cnt, x, acc);
    rgemm<64, 64, true><<<dim3((NN + 63) / 64), dim3(256), 0, stream>>>(acc, x, W1, bias1, y);
    zero_f32<<<dim3(1), dim3(128), 0, stream>>>(stats, 128);
    bn_stats<<<dim3(256), dim3(256), 0, stream>>>(y, stats);
    bn_finalize<<<dim3(1), dim3(64), 0, stream>>>(stats, gamma1, beta1, sc);
    bn_apply<<<dim3(1024), dim3(256), 0, stream>>>(y, sc, nullptr, h1);

    // ---- layer 2 ----
    aggregate<<<dim3(NN / 4), dim3(256), 0, stream>>>(offs, esrt, cnt, h1, acc);
    rgemm<64, 64, true><<<dim3((NN + 63) / 64), dim3(256), 0, stream>>>(acc, h1, W2, bias2, y);
    zero_f32<<<dim3(1), dim3(128), 0, stream>>>(stats, 128);
    bn_stats<<<dim3(256), dim3(256), 0, stream>>>(y, stats);
    bn_finalize<<<dim3(1), dim3(64), 0, stream>>>(stats, gamma2, beta2, sc);
    bn_apply<<<dim3(1024), dim3(256), 0, stream>>>(y, sc, h1, h);

    // ---- layer 3 (output) ----
    aggregate<<<dim3(NN / 4), dim3(256), 0, stream>>>(offs, esrt, cnt, h, acc);
    rgemm<32, 128, false><<<dim3((NN + 127) / 128), dim3(256), 0, stream>>>(acc, h, W3, bias3, out);
}

// Round 5
// 680.210 us; speedup vs baseline: 1.8109x; 1.0286x over previous
//
#include <hip/hip_runtime.h>

#define NN 50000
#define NE 800000
#define RR 8
#define BB 8
#define EPSV 1e-5f
#define SCAN_B ((NN + 255) / 256)   // 196

typedef unsigned short bfu;
typedef __attribute__((ext_vector_type(8))) unsigned short u16x8;

__device__ inline float bf2f(bfu u) { return __uint_as_float(((unsigned)u) << 16); }
__device__ inline bfu f2bf(float f) {
    unsigned u = __float_as_uint(f);
    return (bfu)((u + 0x7fffu + ((u >> 16) & 1u)) >> 16);   // RTNE
}

// ---------------- utility: zero fill ----------------
__global__ void zero_f32(float* __restrict__ p, long n) {
    long i = (long)blockIdx.x * blockDim.x + threadIdx.x;
    long stride = (long)gridDim.x * blockDim.x;
    for (; i < n; i += stride) p[i] = 0.f;
}

// ---------------- once: x (f32) -> xb (bf16) ----------------
__global__ void cvt_bf16(const float* __restrict__ x, bfu* __restrict__ xb, long n) {
    long i = (long)blockIdx.x * blockDim.x + threadIdx.x;
    long stride = (long)gridDim.x * blockDim.x;
    for (; i < n; i += stride) xb[i] = f2bf(x[i]);
}

// ---------------- build Wfull[(R*64 + 64) x O] ----------------
__global__ void build_w(const float* __restrict__ comp, const float* __restrict__ bases,
                        const float* __restrict__ root, float* __restrict__ Wfull,
                        int outDim) {
    int idx = blockIdx.x * blockDim.x + threadIdx.x;
    int tot = (RR * 64 + 64) * outDim;
    if (idx >= tot) return;
    int o = idx % outDim;
    int row = idx / outDim;
    if (row < RR * 64) {
        int r = row >> 6, i = row & 63;
        float s = 0.f;
#pragma unroll
        for (int b = 0; b < BB; ++b)
            s += comp[r * BB + b] * bases[(b * 64 + i) * outDim + o];
        Wfull[idx] = s;
    } else {
        int i = row - RR * 64;
        Wfull[idx] = root[i * outDim + o];
    }
}

// ---------------- once: per-(dst,rel) edge counts ----------------
__global__ void edge_count(const int* __restrict__ ei, const int* __restrict__ et,
                           float* __restrict__ cnt) {
    int i = blockIdx.x * blockDim.x + threadIdx.x;
    int stride = gridDim.x * blockDim.x;
    for (int e = i; e < NE; e += stride) {
        int d = ei[NE + e];
        int r = et[e];
        atomicAdd(&cnt[(size_t)d * RR + r], 1.0f);
    }
}

// ---------------- once: per-dst degree ----------------
__global__ void deg_count(const int* __restrict__ ei, int* __restrict__ deg) {
    int i = blockIdx.x * blockDim.x + threadIdx.x;
    int stride = gridDim.x * blockDim.x;
    for (int e = i; e < NE; e += stride)
        atomicAdd(&deg[ei[NE + e]], 1);
}

// ---------------- once: exclusive scan of deg -> offs ----------------
__global__ void scan1(const int* __restrict__ deg, int* __restrict__ offs, int* __restrict__ bsum) {
    __shared__ int sh[256];
    int b = blockIdx.x, t = threadIdx.x;
    int i = b * 256 + t;
    int v = (i < NN) ? deg[i] : 0;
    sh[t] = v;
    __syncthreads();
    for (int s = 1; s < 256; s <<= 1) {
        int tmp = (t >= s) ? sh[t - s] : 0;
        __syncthreads();
        sh[t] += tmp;
        __syncthreads();
    }
    if (i < NN) offs[i] = sh[t] - v;
    if (t == 255) bsum[b] = sh[255];
}

__global__ void scan2(int* __restrict__ bsum, int* __restrict__ offs) {
    if (threadIdx.x == 0 && blockIdx.x == 0) {
        int run = 0;
        for (int b = 0; b < SCAN_B; ++b) { int t = bsum[b]; bsum[b] = run; run += t; }
        offs[NN] = run;
    }
}

__global__ void scan3(int* __restrict__ offs, const int* __restrict__ bsum) {
    int b = blockIdx.x, t = threadIdx.x;
    int i = b * 256 + t;
    if (i < NN) offs[i] += bsum[b];
}

// ---------------- once: place edges into dst-sorted list (packed src<<3|r) ----------------
__global__ void place(const int* __restrict__ ei, const int* __restrict__ et,
                      const int* __restrict__ offs, int* __restrict__ fill,
                      unsigned* __restrict__ esrt) {
    int i = blockIdx.x * blockDim.x + threadIdx.x;
    int stride = gridDim.x * blockDim.x;
    for (int e = i; e < NE; e += stride) {
        int d = ei[NE + e];
        int pos = offs[d] + atomicAdd(&fill[d], 1);
        esrt[pos] = ((unsigned)ei[e] << 3) | (unsigned)et[e];
    }
}

// ---------------- per layer: gather-aggregate (bf16 in/out), normalized ----------------
__global__ __launch_bounds__(256) void aggregate(const int* __restrict__ offs,
                                                 const unsigned* __restrict__ esrt,
                                                 const float* __restrict__ cnt,
                                                 const bfu* __restrict__ xb,
                                                 bfu* __restrict__ accb) {
    int n = (blockIdx.x * 256 + threadIdx.x) >> 6;   // one wave per dst node
    int lane = threadIdx.x & 63;
    if (n >= NN) return;
    int j0 = offs[n], j1 = offs[n + 1];
    float a0 = 0.f, a1 = 0.f, a2 = 0.f, a3 = 0.f, a4 = 0.f, a5 = 0.f, a6 = 0.f, a7 = 0.f;
    for (int j = j0; j < j1; ++j) {
        unsigned u = esrt[j];                         // wave-uniform load
        int r = __builtin_amdgcn_readfirstlane((int)(u & 7u));
        int s = (int)(u >> 3);
        float v = bf2f(xb[(size_t)s * 64 + lane]);    // coalesced 128B row
        switch (r) {                                  // wave-uniform branch
            case 0: a0 += v; break;
            case 1: a1 += v; break;
            case 2: a2 += v; break;
            case 3: a3 += v; break;
            case 4: a4 += v; break;
            case 5: a5 += v; break;
            case 6: a6 += v; break;
            default: a7 += v; break;
        }
    }
    size_t cb = (size_t)n * RR;
    size_t base = (size_t)n * 512 + lane;
    accb[base + 0 * 64] = f2bf(a0 / fmaxf(cnt[cb + 0], 1.f));
    accb[base + 1 * 64] = f2bf(a1 / fmaxf(cnt[cb + 1], 1.f));
    accb[base + 2 * 64] = f2bf(a2 / fmaxf(cnt[cb + 2], 1.f));
    accb[base + 3 * 64] = f2bf(a3 / fmaxf(cnt[cb + 3], 1.f));
    accb[base + 4 * 64] = f2bf(a4 / fmaxf(cnt[cb + 4], 1.f));
    accb[base + 5 * 64] = f2bf(a5 / fmaxf(cnt[cb + 5], 1.f));
    accb[base + 6 * 64] = f2bf(a6 / fmaxf(cnt[cb + 6], 1.f));
    accb[base + 7 * 64] = f2bf(a7 / fmaxf(cnt[cb + 7], 1.f));
}

// ---------------- per layer: tiled SGEMM with async-stage pipeline ----------------
// V rows (bf16): k<512 from accb, k in [512,576) from xb. f32 LDS tiles, f32 FMA.
template <int O, int MT, bool RELU>
__global__ __launch_bounds__(256) void rgemm(const bfu* __restrict__ accb,
                                             const bfu* __restrict__ xb,
                                             const float* __restrict__ W,
                                             const float* __restrict__ bias,
                                             float* __restrict__ out) {
    constexpr int TX = O / 4;                 // threads along o (16 or 8)
    constexpr int VL = MT / 32;               // short8 V-loads per thread (2 or 4)
    constexpr int WL = O / 16;                // float4 W-loads per thread (4 or 2)
    __shared__ float Vt[MT][72];
    __shared__ float Wt[64][O + 8];
    int t = threadIdx.x;
    int tx = t % TX, ty = t / TX;             // thread tile: 4 outs x 4 nodes
    int n0 = blockIdx.x * MT;
    float a[4][4] = {};
    u16x8 vreg[VL];
    float4 wreg[WL];

    auto load_tile = [&](int kt) {
        int k0 = kt * 64;
#pragma unroll
        for (int l = 0; l < VL; ++l) {
            int idx = t + l * 256;            // over MT*8 chunks of 8 bf16
            int nl = idx >> 3, c8 = idx & 7;
            int n = n0 + nl; if (n >= NN) n = NN - 1;
            const bfu* src = (kt < 8) ? &accb[(size_t)n * 512 + k0 + c8 * 8]
                                      : &xb[(size_t)n * 64 + c8 * 8];
            vreg[l] = *(const u16x8*)src;
        }
#pragma unroll
        for (int l = 0; l < WL; ++l) {
            int idx = t + l * 256;            // over 64*TX float4s
            int kr = idx / TX, og = idx % TX;
            wreg[l] = *(const float4*)&W[(size_t)(k0 + kr) * O + og * 4];
        }
    };
    auto write_tile = [&]() {
#pragma unroll
        for (int l = 0; l < VL; ++l) {
            int idx = t + l * 256;
            int nl = idx >> 3, c8 = idx & 7;
            uint4 u = *(uint4*)&vreg[l];
            float4 lo, hi;
            lo.x = __uint_as_float(u.x << 16); lo.y = __uint_as_float(u.x & 0xffff0000u);
            lo.z = __uint_as_float(u.y << 16); lo.w = __uint_as_float(u.y & 0xffff0000u);
            hi.x = __uint_as_float(u.z << 16); hi.y = __uint_as_float(u.z & 0xffff0000u);
            hi.z = __uint_as_float(u.w << 16); hi.w = __uint_as_float(u.w & 0xffff0000u);
            int m = (nl >> 2) & 3;
            int g0 = (2 * c8) ^ m, g1 = (2 * c8 + 1) ^ m;
            *(float4*)&Vt[nl][g0 * 4] = lo;
            *(float4*)&Vt[nl][g1 * 4] = hi;
        }
#pragma unroll
        for (int l = 0; l < WL; ++l) {
            int idx = t + l * 256;
            int kr = idx / TX, og = idx % TX;
            *(float4*)&Wt[kr][og * 4] = wreg[l];
        }
    };

    load_tile(0);
    for (int kt = 0; kt < 9; ++kt) {
        __syncthreads();                       // prev compute done; LDS free
        write_tile();                          // drains vmcnt for this tile
        if (kt < 8) load_tile(kt + 1);         // next tile's loads fly during compute
        __syncthreads();                       // LDS ready
#pragma unroll
        for (int kk = 0; kk < 64; kk += 4) {
            float4 wv[4], vv[4];
#pragma unroll
            for (int d = 0; d < 4; ++d) wv[d] = *(const float4*)&Wt[kk + d][tx * 4];
#pragma unroll
            for (int i = 0; i < 4; ++i) {
                int nl = ty * 4 + i;
                int gs = (kk >> 2) ^ ((nl >> 2) & 3);
                vv[i] = *(const float4*)&Vt[nl][gs * 4];
            }
#pragma unroll
            for (int i = 0; i < 4; ++i) {
                const float* vf = (const float*)&vv[i];
#pragma unroll
                for (int d = 0; d < 4; ++d) {
                    const float* wf = (const float*)&wv[d];
                    a[i][0] = fmaf(vf[d], wf[0], a[i][0]);
                    a[i][1] = fmaf(vf[d], wf[1], a[i][1]);
                    a[i][2] = fmaf(vf[d], wf[2], a[i][2]);
                    a[i][3] = fmaf(vf[d], wf[3], a[i][3]);
                }
            }
        }
    }
    float4 bv = *(const float4*)&bias[tx * 4];
    const float* bf = (const float*)&bv;
#pragma unroll
    for (int i = 0; i < 4; ++i) {
        int n = n0 + ty * 4 + i;
        if (n < NN) {
            float4 o4;
            float* of = (float*)&o4;
#pragma unroll
            for (int j = 0; j < 4; ++j) {
                float v = a[i][j] + bf[j];
                if (RELU) v = fmaxf(v, 0.f);
                of[j] = v;
            }
            *(float4*)&out[(size_t)n * O + tx * 4] = o4;
        }
    }
}

// ---------------- batchnorm ----------------
__global__ void bn_stats(const float* __restrict__ y, float* __restrict__ stats) {
    int c = threadIdx.x & 63;
    int rg = threadIdx.x >> 6;
    float s = 0.f, q = 0.f;
    for (int n = blockIdx.x * 4 + rg; n < NN; n += gridDim.x * 4) {
        float v = y[(size_t)n * 64 + c];
        s += v;
        q += v * v;
    }
    __shared__ float ls[4][64], lq[4][64];
    ls[rg][c] = s;
    lq[rg][c] = q;
    __syncthreads();
    if (rg == 0) {
        s = ls[0][c] + ls[1][c] + ls[2][c] + ls[3][c];
        q = lq[0][c] + lq[1][c] + lq[2][c] + lq[3][c];
        atomicAdd(&stats[c], s);
        atomicAdd(&stats[64 + c], q);
    }
}

__global__ void bn_finalize(const float* __restrict__ stats, const float* __restrict__ gamma,
                            const float* __restrict__ beta, float* __restrict__ sc) {
    int c = threadIdx.x;
    if (c < 64) {
        float mu = stats[c] / (float)NN;
        float var = stats[64 + c] / (float)NN - mu * mu;
        float scale = gamma[c] * rsqrtf(var + EPSV);
        sc[c] = scale;
        sc[64 + c] = beta[c] - mu * scale;
    }
}

// hb = bf16( y*scale + shift (+ res_bf16) )
__global__ void bn_apply(const float* __restrict__ y, const float* __restrict__ sc,
                         const bfu* __restrict__ resb, bfu* __restrict__ hb) {
    long tot = (long)NN * 64;
    long stride = (long)gridDim.x * blockDim.x;
    for (long i = (long)blockIdx.x * blockDim.x + threadIdx.x; i < tot; i += stride) {
        int c = (int)(i & 63);
        float v = y[i] * sc[c] + sc[64 + c];
        if (resb) v += bf2f(resb[i]);
        hb[i] = f2bf(v);
    }
}

extern "C" void kernel_launch(void* const* d_in, const int* in_sizes, int n_in,
                              void* d_out, int out_size, void* d_ws, size_t ws_size,
                              hipStream_t stream) {
    const float* x      = (const float*)d_in[0];
    const int*   ei     = (const int*)d_in[1];
    const int*   et     = (const int*)d_in[2];
    const float* comp1  = (const float*)d_in[3];
    const float* bases1 = (const float*)d_in[4];
    const float* root1  = (const float*)d_in[5];
    const float* bias1  = (const float*)d_in[6];
    const float* comp2  = (const float*)d_in[7];
    const float* bases2 = (const float*)d_in[8];
    const float* root2  = (const float*)d_in[9];
    const float* bias2  = (const float*)d_in[10];
    const float* comp3  = (const float*)d_in[11];
    const float* bases3 = (const float*)d_in[12];
    const float* root3  = (const float*)d_in[13];
    const float* bias3  = (const float*)d_in[14];
    const float* gamma1 = (const float*)d_in[15];
    const float* beta1  = (const float*)d_in[16];
    const float* gamma2 = (const float*)d_in[17];
    const float* beta2  = (const float*)d_in[18];
    float* out = (float*)d_out;

    float* ws = (float*)d_ws;
    size_t off = 0;
    float* W1 = ws + off; off += 576 * 64;
    float* W2 = ws + off; off += 576 * 64;
    float* W3 = ws + off; off += 576 * 32;
    float* stats = ws + off; off += 128;
    float* sc = ws + off; off += 128;
    float* cnt = ws + off; off += (size_t)NN * RR;
    float* y  = ws + off; off += (size_t)NN * 64;
    bfu* accb = (bfu*)(ws + off); off += (size_t)NN * 256;   // N*512 bf16
    bfu* xb   = (bfu*)(ws + off); off += (size_t)NN * 32;    // N*64 bf16
    bfu* h1b  = (bfu*)(ws + off); off += (size_t)NN * 32;
    bfu* hb   = (bfu*)(ws + off); off += (size_t)NN * 32;
    int* deg  = (int*)(ws + off); off += NN;
    int* offs = (int*)(ws + off); off += NN + 4;
    int* fill = (int*)(ws + off); off += NN;
    int* bsum = (int*)(ws + off); off += 256;
    unsigned* esrt = (unsigned*)(ws + off); off += NE;

    // ---- once: weights + bf16 x + counts + CSR ----
    build_w<<<dim3((576 * 64 + 255) / 256), dim3(256), 0, stream>>>(comp1, bases1, root1, W1, 64);
    build_w<<<dim3((576 * 64 + 255) / 256), dim3(256), 0, stream>>>(comp2, bases2, root2, W2, 64);
    build_w<<<dim3((576 * 32 + 255) / 256), dim3(256), 0, stream>>>(comp3, bases3, root3, W3, 32);
    cvt_bf16<<<dim3(512), dim3(256), 0, stream>>>(x, xb, (long)NN * 64);
    zero_f32<<<dim3(512), dim3(256), 0, stream>>>(cnt, (long)NN * RR);
    zero_f32<<<dim3(128), dim3(256), 0, stream>>>((float*)deg, NN);
    zero_f32<<<dim3(128), dim3(256), 0, stream>>>((float*)fill, NN);
    edge_count<<<dim3(1024), dim3(256), 0, stream>>>(ei, et, cnt);
    deg_count<<<dim3(1024), dim3(256), 0, stream>>>(ei, deg);
    scan1<<<dim3(SCAN_B), dim3(256), 0, stream>>>(deg, offs, bsum);
    scan2<<<dim3(1), dim3(64), 0, stream>>>(bsum, offs);
    scan3<<<dim3(SCAN_B), dim3(256), 0, stream>>>(offs, bsum);
    place<<<dim3(1024), dim3(256), 0, stream>>>(ei, et, offs, fill, esrt);

    // ---- layer 1 ----
    aggregate<<<dim3(NN / 4), dim3(256), 0, stream>>>(offs, esrt, cnt, xb, accb);
    rgemm<64, 64, true><<<dim3((NN + 63) / 64), dim3(256), 0, stream>>>(accb, xb, W1, bias1, y);
    zero_f32<<<dim3(1), dim3(128), 0, stream>>>(stats, 128);
    bn_stats<<<dim3(256), dim3(256), 0, stream>>>(y, stats);
    bn_finalize<<<dim3(1), dim3(64), 0, stream>>>(stats, gamma1, beta1, sc);
    bn_apply<<<dim3(1024), dim3(256), 0, stream>>>(y, sc, nullptr, h1b);

    // ---- layer 2 ----
    aggregate<<<dim3(NN / 4), dim3(256), 0, stream>>>(offs, esrt, cnt, h1b, accb);
    rgemm<64, 64, true><<<dim3((NN + 63) / 64), dim3(256), 0, stream>>>(accb, h1b, W2, bias2, y);
    zero_f32<<<dim3(1), dim3(128), 0, stream>>>(stats, 128);
    bn_stats<<<dim3(256), dim3(256), 0, stream>>>(y, stats);
    bn_finalize<<<dim3(1), dim3(64), 0, stream>>>(stats, gamma2, beta2, sc);
    bn_apply<<<dim3(1024), dim3(256), 0, stream>>>(y, sc, h1b, hb);

    // ---- layer 3 (output) ----
    aggregate<<<dim3(NN / 4), dim3(256), 0, stream>>>(offs, esrt, cnt, hb, accb);
    rgemm<32, 128, false><<<dim3((NN + 127) / 128), dim3(256), 0, stream>>>(accb, hb, W3, bias3, out);
}

// Round 6
// 418.353 us; speedup vs baseline: 2.9443x; 1.6259x over previous
//
#include <hip/hip_runtime.h>

#define NN 50000
#define NE 800000
#define RR 8
#define BB 8
#define EPSV 1e-5f
#define SCAN_B ((NN + 255) / 256)   // 196

typedef unsigned short bfu;
typedef __attribute__((ext_vector_type(8))) short bf16x8;
typedef __attribute__((ext_vector_type(4))) float f32x4;

__device__ inline float bf2f(bfu u) { return __uint_as_float(((unsigned)u) << 16); }
__device__ inline bfu f2bf(float f) {
    unsigned u = __float_as_uint(f);
    return (bfu)((u + 0x7fffu + ((u >> 16) & 1u)) >> 16);   // RTNE
}

// ---------------- utility: zero fill ----------------
__global__ void zero_f32(float* __restrict__ p, long n) {
    long i = (long)blockIdx.x * blockDim.x + threadIdx.x;
    long stride = (long)gridDim.x * blockDim.x;
    for (; i < n; i += stride) p[i] = 0.f;
}

// ---------------- once: x (f32) -> xb (bf16) ----------------
__global__ void cvt_bf16(const float* __restrict__ x, bfu* __restrict__ xb, long n) {
    long i = (long)blockIdx.x * blockDim.x + threadIdx.x;
    long stride = (long)gridDim.x * blockDim.x;
    for (; i < n; i += stride) xb[i] = f2bf(x[i]);
}

// ---------------- build W packed for MFMA B-fragments (bf16) ----------------
// logical W[k][o], k in [0,576): k<512 -> sum_b comp[k>>6,b]*bases[b,k&63,o]; else root[k-512,o]
// packed: Wp[ ((kt*(O/16) + (o>>4))*64 + ((kk>>3)<<4 | (o&15)) )*8 + (kk&7) ],  kt=k>>5, kk=k&31
__global__ void build_w_packed(const float* __restrict__ comp, const float* __restrict__ bases,
                               const float* __restrict__ root, bfu* __restrict__ Wp, int O) {
    int idx = blockIdx.x * blockDim.x + threadIdx.x;
    int tot = 576 * O;
    if (idx >= tot) return;
    int k = idx / O, o = idx % O;
    float val;
    if (k < 512) {
        int r = k >> 6, i = k & 63;
        val = 0.f;
#pragma unroll
        for (int b = 0; b < BB; ++b)
            val += comp[r * BB + b] * bases[(b * 64 + i) * O + o];
    } else {
        val = root[(k - 512) * O + o];
    }
    int kt = k >> 5, kk = k & 31;
    int lane = ((kk >> 3) << 4) | (o & 15);
    int pos = ((kt * (O / 16) + (o >> 4)) * 64 + lane) * 8 + (kk & 7);
    Wp[pos] = f2bf(val);
}

// ---------------- once: per-(dst,rel) edge counts ----------------
__global__ void edge_count(const int* __restrict__ ei, const int* __restrict__ et,
                           float* __restrict__ cnt) {
    int i = blockIdx.x * blockDim.x + threadIdx.x;
    int stride = gridDim.x * blockDim.x;
    for (int e = i; e < NE; e += stride) {
        int d = ei[NE + e];
        int r = et[e];
        atomicAdd(&cnt[(size_t)d * RR + r], 1.0f);
    }
}

// ---------------- once: per-dst degree ----------------
__global__ void deg_count(const int* __restrict__ ei, int* __restrict__ deg) {
    int i = blockIdx.x * blockDim.x + threadIdx.x;
    int stride = gridDim.x * blockDim.x;
    for (int e = i; e < NE; e += stride)
        atomicAdd(&deg[ei[NE + e]], 1);
}

// ---------------- once: exclusive scan of deg -> offs ----------------
__global__ void scan1(const int* __restrict__ deg, int* __restrict__ offs, int* __restrict__ bsum) {
    __shared__ int sh[256];
    int b = blockIdx.x, t = threadIdx.x;
    int i = b * 256 + t;
    int v = (i < NN) ? deg[i] : 0;
    sh[t] = v;
    __syncthreads();
    for (int s = 1; s < 256; s <<= 1) {
        int tmp = (t >= s) ? sh[t - s] : 0;
        __syncthreads();
        sh[t] += tmp;
        __syncthreads();
    }
    if (i < NN) offs[i] = sh[t] - v;
    if (t == 255) bsum[b] = sh[255];
}

__global__ void scan2(int* __restrict__ bsum, int* __restrict__ offs) {
    if (threadIdx.x == 0 && blockIdx.x == 0) {
        int run = 0;
        for (int b = 0; b < SCAN_B; ++b) { int t = bsum[b]; bsum[b] = run; run += t; }
        offs[NN] = run;
    }
}

__global__ void scan3(int* __restrict__ offs, const int* __restrict__ bsum) {
    int b = blockIdx.x, t = threadIdx.x;
    int i = b * 256 + t;
    if (i < NN) offs[i] += bsum[b];
}

// ---------------- once: place edges into dst-sorted list (packed src<<3|r) ----------------
__global__ void place(const int* __restrict__ ei, const int* __restrict__ et,
                      const int* __restrict__ offs, int* __restrict__ fill,
                      unsigned* __restrict__ esrt) {
    int i = blockIdx.x * blockDim.x + threadIdx.x;
    int stride = gridDim.x * blockDim.x;
    for (int e = i; e < NE; e += stride) {
        int d = ei[NE + e];
        int pos = offs[d] + atomicAdd(&fill[d], 1);
        esrt[pos] = ((unsigned)ei[e] << 3) | (unsigned)et[e];
    }
}

// ---------------- per layer: gather-aggregate (bf16 in/out), 4-deep pipelined ----------------
#define ACCUM(U, V)                                              \
    switch (__builtin_amdgcn_readfirstlane((int)((U) & 7u))) {   \
        case 0: a0 += (V); break;                                \
        case 1: a1 += (V); break;                                \
        case 2: a2 += (V); break;                                \
        case 3: a3 += (V); break;                                \
        case 4: a4 += (V); break;                                \
        case 5: a5 += (V); break;                                \
        case 6: a6 += (V); break;                                \
        default: a7 += (V); break;                               \
    }

__global__ __launch_bounds__(256) void aggregate(const int* __restrict__ offs,
                                                 const unsigned* __restrict__ esrt,
                                                 const float* __restrict__ cnt,
                                                 const bfu* __restrict__ xb,
                                                 bfu* __restrict__ accb) {
    int n = (blockIdx.x * 256 + threadIdx.x) >> 6;   // one wave per dst node
    int lane = threadIdx.x & 63;
    if (n >= NN) return;
    int j0 = offs[n], j1 = offs[n + 1];
    float a0 = 0.f, a1 = 0.f, a2 = 0.f, a3 = 0.f, a4 = 0.f, a5 = 0.f, a6 = 0.f, a7 = 0.f;
    int j = j0;
    for (; j + 4 <= j1; j += 4) {
        unsigned u0 = esrt[j], u1 = esrt[j + 1], u2 = esrt[j + 2], u3 = esrt[j + 3];
        float v0 = bf2f(xb[(size_t)(u0 >> 3) * 64 + lane]);   // 4 gathers in flight
        float v1 = bf2f(xb[(size_t)(u1 >> 3) * 64 + lane]);
        float v2 = bf2f(xb[(size_t)(u2 >> 3) * 64 + lane]);
        float v3 = bf2f(xb[(size_t)(u3 >> 3) * 64 + lane]);
        ACCUM(u0, v0); ACCUM(u1, v1); ACCUM(u2, v2); ACCUM(u3, v3);
    }
    for (; j < j1; ++j) {
        unsigned u = esrt[j];
        float v = bf2f(xb[(size_t)(u >> 3) * 64 + lane]);
        ACCUM(u, v);
    }
    size_t cb = (size_t)n * RR;
    size_t base = (size_t)n * 512 + lane;
    accb[base + 0 * 64] = f2bf(a0 / fmaxf(cnt[cb + 0], 1.f));
    accb[base + 1 * 64] = f2bf(a1 / fmaxf(cnt[cb + 1], 1.f));
    accb[base + 2 * 64] = f2bf(a2 / fmaxf(cnt[cb + 2], 1.f));
    accb[base + 3 * 64] = f2bf(a3 / fmaxf(cnt[cb + 3], 1.f));
    accb[base + 4 * 64] = f2bf(a4 / fmaxf(cnt[cb + 4], 1.f));
    accb[base + 5 * 64] = f2bf(a5 / fmaxf(cnt[cb + 5], 1.f));
    accb[base + 6 * 64] = f2bf(a6 / fmaxf(cnt[cb + 6], 1.f));
    accb[base + 7 * 64] = f2bf(a7 / fmaxf(cnt[cb + 7], 1.f));
}

// ---------------- per layer: MFMA GEMM, no LDS ----------------
// wave -> 16 nodes x O cols; A-frag: lane holds V[nb+(lane&15)][kt*32+(lane>>4)*8 ..+7]
// B-frag from packed Wp (one 16B coalesced load); C: col=lane&15, row=(lane>>4)*4+reg
template <int O, bool RELU>
__global__ __launch_bounds__(256) void rgemm_mfma(const bfu* __restrict__ accb,
                                                  const bfu* __restrict__ xb,
                                                  const bfu* __restrict__ Wp,
                                                  const float* __restrict__ bias,
                                                  float* __restrict__ out) {
    constexpr int CT = O / 16;
    int wave = threadIdx.x >> 6, lane = threadIdx.x & 63;
    int nb = blockIdx.x * 64 + wave * 16;
    int arow = lane & 15, kh = lane >> 4;
    int nA = nb + arow; if (nA >= NN) nA = NN - 1;
    const bfu* aBase = &accb[(size_t)nA * 512 + kh * 8];
    const bfu* xBase = &xb[(size_t)nA * 64 + kh * 8];
    f32x4 acc[CT];
#pragma unroll
    for (int ct = 0; ct < CT; ++ct) acc[ct] = (f32x4){0.f, 0.f, 0.f, 0.f};
#pragma unroll
    for (int kt = 0; kt < 18; ++kt) {
        bf16x8 af = (kt < 16) ? *(const bf16x8*)(aBase + kt * 32)
                              : *(const bf16x8*)(xBase + (kt - 16) * 32);
#pragma unroll
        for (int ct = 0; ct < CT; ++ct) {
            bf16x8 bfv = *(const bf16x8*)&Wp[((size_t)(kt * CT + ct) * 64 + lane) * 8];
            acc[ct] = __builtin_amdgcn_mfma_f32_16x16x32_bf16(af, bfv, acc[ct], 0, 0, 0);
        }
    }
#pragma unroll
    for (int ct = 0; ct < CT; ++ct) {
        int col = ct * 16 + arow;
        float b = bias[col];
#pragma unroll
        for (int j = 0; j < 4; ++j) {
            int n = nb + kh * 4 + j;
            if (n < NN) {
                float v = acc[ct][j] + b;
                if (RELU) v = fmaxf(v, 0.f);
                out[(size_t)n * O + col] = v;
            }
        }
    }
}

// ---------------- batchnorm ----------------
__global__ void bn_stats(const float* __restrict__ y, float* __restrict__ stats) {
    int c = threadIdx.x & 63;
    int rg = threadIdx.x >> 6;
    float s = 0.f, q = 0.f;
    for (int n = blockIdx.x * 4 + rg; n < NN; n += gridDim.x * 4) {
        float v = y[(size_t)n * 64 + c];
        s += v;
        q += v * v;
    }
    __shared__ float ls[4][64], lq[4][64];
    ls[rg][c] = s;
    lq[rg][c] = q;
    __syncthreads();
    if (rg == 0) {
        s = ls[0][c] + ls[1][c] + ls[2][c] + ls[3][c];
        q = lq[0][c] + lq[1][c] + lq[2][c] + lq[3][c];
        atomicAdd(&stats[c], s);
        atomicAdd(&stats[64 + c], q);
    }
}

__global__ void bn_finalize(const float* __restrict__ stats, const float* __restrict__ gamma,
                            const float* __restrict__ beta, float* __restrict__ sc) {
    int c = threadIdx.x;
    if (c < 64) {
        float mu = stats[c] / (float)NN;
        float var = stats[64 + c] / (float)NN - mu * mu;
        float scale = gamma[c] * rsqrtf(var + EPSV);
        sc[c] = scale;
        sc[64 + c] = beta[c] - mu * scale;
    }
}

// hb = bf16( y*scale + shift (+ res_bf16) )
__global__ void bn_apply(const float* __restrict__ y, const float* __restrict__ sc,
                         const bfu* __restrict__ resb, bfu* __restrict__ hb) {
    long tot = (long)NN * 64;
    long stride = (long)gridDim.x * blockDim.x;
    for (long i = (long)blockIdx.x * blockDim.x + threadIdx.x; i < tot; i += stride) {
        int c = (int)(i & 63);
        float v = y[i] * sc[c] + sc[64 + c];
        if (resb) v += bf2f(resb[i]);
        hb[i] = f2bf(v);
    }
}

extern "C" void kernel_launch(void* const* d_in, const int* in_sizes, int n_in,
                              void* d_out, int out_size, void* d_ws, size_t ws_size,
                              hipStream_t stream) {
    const float* x      = (const float*)d_in[0];
    const int*   ei     = (const int*)d_in[1];
    const int*   et     = (const int*)d_in[2];
    const float* comp1  = (const float*)d_in[3];
    const float* bases1 = (const float*)d_in[4];
    const float* root1  = (const float*)d_in[5];
    const float* bias1  = (const float*)d_in[6];
    const float* comp2  = (const float*)d_in[7];
    const float* bases2 = (const float*)d_in[8];
    const float* root2  = (const float*)d_in[9];
    const float* bias2  = (const float*)d_in[10];
    const float* comp3  = (const float*)d_in[11];
    const float* bases3 = (const float*)d_in[12];
    const float* root3  = (const float*)d_in[13];
    const float* bias3  = (const float*)d_in[14];
    const float* gamma1 = (const float*)d_in[15];
    const float* beta1  = (const float*)d_in[16];
    const float* gamma2 = (const float*)d_in[17];
    const float* beta2  = (const float*)d_in[18];
    float* out = (float*)d_out;

    float* ws = (float*)d_ws;
    size_t off = 0;
    bfu* Wp1 = (bfu*)(ws + off); off += 18432;               // 18*4*64*8 bf16
    bfu* Wp2 = (bfu*)(ws + off); off += 18432;
    bfu* Wp3 = (bfu*)(ws + off); off += 9216;                // 18*2*64*8 bf16
    float* stats = ws + off; off += 128;
    float* sc = ws + off; off += 128;
    float* cnt = ws + off; off += (size_t)NN * RR;
    float* y  = ws + off; off += (size_t)NN * 64;
    bfu* accb = (bfu*)(ws + off); off += (size_t)NN * 256;   // N*512 bf16
    bfu* xb   = (bfu*)(ws + off); off += (size_t)NN * 32;    // N*64 bf16
    bfu* h1b  = (bfu*)(ws + off); off += (size_t)NN * 32;
    bfu* hb   = (bfu*)(ws + off); off += (size_t)NN * 32;
    int* deg  = (int*)(ws + off); off += NN;
    int* offs = (int*)(ws + off); off += NN + 4;
    int* fill = (int*)(ws + off); off += NN;
    int* bsum = (int*)(ws + off); off += 256;
    unsigned* esrt = (unsigned*)(ws + off); off += NE;

    // ---- once: packed weights + bf16 x + counts + CSR ----
    build_w_packed<<<dim3((576 * 64 + 255) / 256), dim3(256), 0, stream>>>(comp1, bases1, root1, Wp1, 64);
    build_w_packed<<<dim3((576 * 64 + 255) / 256), dim3(256), 0, stream>>>(comp2, bases2, root2, Wp2, 64);
    build_w_packed<<<dim3((576 * 32 + 255) / 256), dim3(256), 0, stream>>>(comp3, bases3, root3, Wp3, 32);
    cvt_bf16<<<dim3(512), dim3(256), 0, stream>>>(x, xb, (long)NN * 64);
    zero_f32<<<dim3(512), dim3(256), 0, stream>>>(cnt, (long)NN * RR);
    zero_f32<<<dim3(128), dim3(256), 0, stream>>>((float*)deg, NN);
    zero_f32<<<dim3(128), dim3(256), 0, stream>>>((float*)fill, NN);
    edge_count<<<dim3(1024), dim3(256), 0, stream>>>(ei, et, cnt);
    deg_count<<<dim3(1024), dim3(256), 0, stream>>>(ei, deg);
    scan1<<<dim3(SCAN_B), dim3(256), 0, stream>>>(deg, offs, bsum);
    scan2<<<dim3(1), dim3(64), 0, stream>>>(bsum, offs);
    scan3<<<dim3(SCAN_B), dim3(256), 0, stream>>>(offs, bsum);
    place<<<dim3(1024), dim3(256), 0, stream>>>(ei, et, offs, fill, esrt);

    // ---- layer 1 ----
    aggregate<<<dim3(NN / 4), dim3(256), 0, stream>>>(offs, esrt, cnt, xb, accb);
    rgemm_mfma<64, true><<<dim3((NN + 63) / 64), dim3(256), 0, stream>>>(accb, xb, Wp1, bias1, y);
    zero_f32<<<dim3(1), dim3(128), 0, stream>>>(stats, 128);
    bn_stats<<<dim3(256), dim3(256), 0, stream>>>(y, stats);
    bn_finalize<<<dim3(1), dim3(64), 0, stream>>>(stats, gamma1, beta1, sc);
    bn_apply<<<dim3(1024), dim3(256), 0, stream>>>(y, sc, nullptr, h1b);

    // ---- layer 2 ----
    aggregate<<<dim3(NN / 4), dim3(256), 0, stream>>>(offs, esrt, cnt, h1b, accb);
    rgemm_mfma<64, true><<<dim3((NN + 63) / 64), dim3(256), 0, stream>>>(accb, h1b, Wp2, bias2, y);
    zero_f32<<<dim3(1), dim3(128), 0, stream>>>(stats, 128);
    bn_stats<<<dim3(256), dim3(256), 0, stream>>>(y, stats);
    bn_finalize<<<dim3(1), dim3(64), 0, stream>>>(stats, gamma2, beta2, sc);
    bn_apply<<<dim3(1024), dim3(256), 0, stream>>>(y, sc, h1b, hb);

    // ---- layer 3 (output) ----
    aggregate<<<dim3(NN / 4), dim3(256), 0, stream>>>(offs, esrt, cnt, hb, accb);
    rgemm_mfma<32, false><<<dim3((NN + 63) / 64), dim3(256), 0, stream>>>(accb, hb, Wp3, bias3, out);
}

// Round 7
// 345.582 us; speedup vs baseline: 3.5643x; 1.2106x over previous
//
#include <hip/hip_runtime.h>

#define NN 50000
#define NE 800000
#define RR 8
#define BB 8
#define EPSV 1e-5f
#define SCAN_B ((NN + 255) / 256)   // 196

typedef unsigned short bfu;
typedef __attribute__((ext_vector_type(8))) short bf16x8;
typedef __attribute__((ext_vector_type(4))) float f32x4;

__device__ inline float bf2f(bfu u) { return __uint_as_float(((unsigned)u) << 16); }
__device__ inline bfu f2bf(float f) {
    unsigned u = __float_as_uint(f);
    return (bfu)((u + 0x7fffu + ((u >> 16) & 1u)) >> 16);   // RTNE
}

// ---------------- utility: zero fill ----------------
__global__ void zero_f32(float* __restrict__ p, long n) {
    long i = (long)blockIdx.x * blockDim.x + threadIdx.x;
    long stride = (long)gridDim.x * blockDim.x;
    for (; i < n; i += stride) p[i] = 0.f;
}

// ---------------- once: x (f32) -> xb (bf16) ----------------
__global__ void cvt_bf16(const float* __restrict__ x, bfu* __restrict__ xb, long n) {
    long i = (long)blockIdx.x * blockDim.x + threadIdx.x;
    long stride = (long)gridDim.x * blockDim.x;
    for (; i < n; i += stride) xb[i] = f2bf(x[i]);
}

// ---------------- build W packed for MFMA B-fragments (bf16) ----------------
// logical W[k][o], k in [0,576): k<512 -> sum_b comp[k>>6,b]*bases[b,k&63,o]; else root[k-512,o]
__global__ void build_w_packed(const float* __restrict__ comp, const float* __restrict__ bases,
                               const float* __restrict__ root, bfu* __restrict__ Wp, int O) {
    int idx = blockIdx.x * blockDim.x + threadIdx.x;
    int tot = 576 * O;
    if (idx >= tot) return;
    int k = idx / O, o = idx % O;
    float val;
    if (k < 512) {
        int r = k >> 6, i = k & 63;
        val = 0.f;
#pragma unroll
        for (int b = 0; b < BB; ++b)
            val += comp[r * BB + b] * bases[(b * 64 + i) * O + o];
    } else {
        val = root[(k - 512) * O + o];
    }
    int kt = k >> 5, kk = k & 31;
    int lane = ((kk >> 3) << 4) | (o & 15);
    int pos = ((kt * (O / 16) + (o >> 4)) * 64 + lane) * 8 + (kk & 7);
    Wp[pos] = f2bf(val);
}

// ---------------- once: per-(dst,rel) edge counts ----------------
__global__ void edge_count(const int* __restrict__ ei, const int* __restrict__ et,
                           float* __restrict__ cnt) {
    int i = blockIdx.x * blockDim.x + threadIdx.x;
    int stride = gridDim.x * blockDim.x;
    for (int e = i; e < NE; e += stride) {
        int d = ei[NE + e];
        int r = et[e];
        atomicAdd(&cnt[(size_t)d * RR + r], 1.0f);
    }
}

// ---------------- once: exclusive scan of degree (= row-sum of cnt) -> offs ----------------
__global__ void scan1(const float* __restrict__ cnt, int* __restrict__ offs, int* __restrict__ bsum) {
    __shared__ int sh[256];
    int b = blockIdx.x, t = threadIdx.x;
    int i = b * 256 + t;
    int v = 0;
    if (i < NN) {
        float s = 0.f;
#pragma unroll
        for (int r = 0; r < RR; ++r) s += cnt[(size_t)i * RR + r];
        v = (int)s;
    }
    sh[t] = v;
    __syncthreads();
    for (int s = 1; s < 256; s <<= 1) {
        int tmp = (t >= s) ? sh[t - s] : 0;
        __syncthreads();
        sh[t] += tmp;
        __syncthreads();
    }
    if (i < NN) offs[i] = sh[t] - v;
    if (t == 255) bsum[b] = sh[255];
}

__global__ void scan2(int* __restrict__ bsum, int* __restrict__ offs) {
    if (threadIdx.x == 0 && blockIdx.x == 0) {
        int run = 0;
        for (int b = 0; b < SCAN_B; ++b) { int t = bsum[b]; bsum[b] = run; run += t; }
        offs[NN] = run;
    }
}

__global__ void scan3(int* __restrict__ offs, const int* __restrict__ bsum) {
    int b = blockIdx.x, t = threadIdx.x;
    int i = b * 256 + t;
    if (i < NN) offs[i] += bsum[b];
}

// ---------------- once: place edges into dst-sorted list (packed src<<3|r) ----------------
__global__ void place(const int* __restrict__ ei, const int* __restrict__ et,
                      const int* __restrict__ offs, int* __restrict__ fill,
                      unsigned* __restrict__ esrt) {
    int i = blockIdx.x * blockDim.x + threadIdx.x;
    int stride = gridDim.x * blockDim.x;
    for (int e = i; e < NE; e += stride) {
        int d = ei[NE + e];
        int pos = offs[d] + atomicAdd(&fill[d], 1);
        esrt[pos] = ((unsigned)ei[e] << 3) | (unsigned)et[e];
    }
}

// ---------------- fused per layer: aggregate into LDS A-frags + MFMA GEMM ----------------
// block = 256 thr = 4 waves = 16 nodes. Wave w aggregates nodes w*4..w*4+3 (8 per-relation
// accumulators in regs), normalizes, writes bf16 into LDS in MFMA A-fragment layout
// (granule-XOR-swizzled). Then wave w computes output cols [16w,16w+16) via 18 MFMAs.
#define ACCUM(U, V)                                              \
    switch (__builtin_amdgcn_readfirstlane((int)((U) & 7u))) {   \
        case 0: a0 += (V); break;                                \
        case 1: a1 += (V); break;                                \
        case 2: a2 += (V); break;                                \
        case 3: a3 += (V); break;                                \
        case 4: a4 += (V); break;                                \
        case 5: a5 += (V); break;                                \
        case 6: a6 += (V); break;                                \
        default: a7 += (V); break;                               \
    }

template <int O, bool RELU>
__global__ __launch_bounds__(256) void agg_gemm(const int* __restrict__ offs,
                                                const unsigned* __restrict__ esrt,
                                                const float* __restrict__ cnt,
                                                const bfu* __restrict__ xb,
                                                const bfu* __restrict__ Wp,
                                                const float* __restrict__ bias,
                                                float* __restrict__ outp) {
    constexpr int CT = O / 16;
    __shared__ bfu Af[1152 * 8];                     // 18 k-tiles x 64 lanes x 8 bf16 = 18KB
    int wave = threadIdx.x >> 6, lane = threadIdx.x & 63;
    int n0 = blockIdx.x * 16;
    int c = lane;
    int swz_lo = ((c >> 3) & 3) << 4;                // frag-lane high bits from kk>>3

#pragma unroll 1
    for (int i = 0; i < 4; ++i) {
        int row = wave * 4 + i;
        int n = n0 + row;
        int j0 = offs[n], j1 = offs[n + 1];
        float a0 = 0.f, a1 = 0.f, a2 = 0.f, a3 = 0.f, a4 = 0.f, a5 = 0.f, a6 = 0.f, a7 = 0.f;
        int j = j0;
        for (; j + 4 <= j1; j += 4) {
            unsigned u0 = esrt[j], u1 = esrt[j + 1], u2 = esrt[j + 2], u3 = esrt[j + 3];
            float v0 = bf2f(xb[(size_t)(u0 >> 3) * 64 + lane]);
            float v1 = bf2f(xb[(size_t)(u1 >> 3) * 64 + lane]);
            float v2 = bf2f(xb[(size_t)(u2 >> 3) * 64 + lane]);
            float v3 = bf2f(xb[(size_t)(u3 >> 3) * 64 + lane]);
            ACCUM(u0, v0); ACCUM(u1, v1); ACCUM(u2, v2); ACCUM(u3, v3);
        }
        for (; j < j1; ++j) {
            unsigned u = esrt[j];
            float v = bf2f(xb[(size_t)(u >> 3) * 64 + lane]);
            ACCUM(u, v);
        }
        // normalize + write A-fragments: value (row, k=r*64+c) -> granule g=kt*64|fraglane
#define WR(r, ar) {                                                            \
        float inv = 1.f / fmaxf(cnt[(size_t)n * RR + (r)], 1.f);               \
        bfu bv = f2bf((ar) * inv);                                             \
        int g = (2 * (r) + (c >> 5)) * 64 + (row | swz_lo);                    \
        int gs = g ^ ((g >> 3) & 7) ^ ((g >> 6) & 7);                          \
        Af[gs * 8 + (c & 7)] = bv; }
        WR(0, a0) WR(1, a1) WR(2, a2) WR(3, a3)
        WR(4, a4) WR(5, a5) WR(6, a6) WR(7, a7)
#undef WR
        {   // root-input columns k=512+c  (kt = 16,17)
            bfu bv = xb[(size_t)n * 64 + lane];
            int g = (16 + (c >> 5)) * 64 + (row | swz_lo);
            int gs = g ^ ((g >> 3) & 7) ^ ((g >> 6) & 7);
            Af[gs * 8 + (c & 7)] = bv;
        }
    }
    __syncthreads();

    int ct = wave;
    if (CT == 4 || ct < CT) {
        f32x4 acc = (f32x4){0.f, 0.f, 0.f, 0.f};
#pragma unroll
        for (int kt = 0; kt < 18; ++kt) {
            int g = kt * 64 + lane;
            int gs = g ^ ((g >> 3) & 7) ^ ((g >> 6) & 7);
            bf16x8 af = *(const bf16x8*)&Af[gs * 8];
            bf16x8 bfv = *(const bf16x8*)&Wp[((size_t)(kt * CT + ct) * 64 + lane) * 8];
            acc = __builtin_amdgcn_mfma_f32_16x16x32_bf16(af, bfv, acc, 0, 0, 0);
        }
        int col = ct * 16 + (lane & 15);
        float b = bias[col];
#pragma unroll
        for (int jj = 0; jj < 4; ++jj) {
            int row = (lane >> 4) * 4 + jj;
            float v = acc[jj] + b;
            if (RELU) v = fmaxf(v, 0.f);
            outp[(size_t)(n0 + row) * O + col] = v;
        }
    }
}

// ---------------- batchnorm ----------------
__global__ void bn_stats(const float* __restrict__ y, float* __restrict__ stats) {
    int c = threadIdx.x & 63;
    int rg = threadIdx.x >> 6;
    float s = 0.f, q = 0.f;
    for (int n = blockIdx.x * 4 + rg; n < NN; n += gridDim.x * 4) {
        float v = y[(size_t)n * 64 + c];
        s += v;
        q += v * v;
    }
    __shared__ float ls[4][64], lq[4][64];
    ls[rg][c] = s;
    lq[rg][c] = q;
    __syncthreads();
    if (rg == 0) {
        s = ls[0][c] + ls[1][c] + ls[2][c] + ls[3][c];
        q = lq[0][c] + lq[1][c] + lq[2][c] + lq[3][c];
        atomicAdd(&stats[c], s);
        atomicAdd(&stats[64 + c], q);
    }
}

__global__ void bn_finalize(const float* __restrict__ stats, const float* __restrict__ gamma,
                            const float* __restrict__ beta, float* __restrict__ sc) {
    int c = threadIdx.x;
    if (c < 64) {
        float mu = stats[c] / (float)NN;
        float var = stats[64 + c] / (float)NN - mu * mu;
        float scale = gamma[c] * rsqrtf(var + EPSV);
        sc[c] = scale;
        sc[64 + c] = beta[c] - mu * scale;
    }
}

// hb = bf16( y*scale + shift (+ res_bf16) )
__global__ void bn_apply(const float* __restrict__ y, const float* __restrict__ sc,
                         const bfu* __restrict__ resb, bfu* __restrict__ hb) {
    long tot = (long)NN * 64;
    long stride = (long)gridDim.x * blockDim.x;
    for (long i = (long)blockIdx.x * blockDim.x + threadIdx.x; i < tot; i += stride) {
        int c = (int)(i & 63);
        float v = y[i] * sc[c] + sc[64 + c];
        if (resb) v += bf2f(resb[i]);
        hb[i] = f2bf(v);
    }
}

extern "C" void kernel_launch(void* const* d_in, const int* in_sizes, int n_in,
                              void* d_out, int out_size, void* d_ws, size_t ws_size,
                              hipStream_t stream) {
    const float* x      = (const float*)d_in[0];
    const int*   ei     = (const int*)d_in[1];
    const int*   et     = (const int*)d_in[2];
    const float* comp1  = (const float*)d_in[3];
    const float* bases1 = (const float*)d_in[4];
    const float* root1  = (const float*)d_in[5];
    const float* bias1  = (const float*)d_in[6];
    const float* comp2  = (const float*)d_in[7];
    const float* bases2 = (const float*)d_in[8];
    const float* root2  = (const float*)d_in[9];
    const float* bias2  = (const float*)d_in[10];
    const float* comp3  = (const float*)d_in[11];
    const float* bases3 = (const float*)d_in[12];
    const float* root3  = (const float*)d_in[13];
    const float* bias3  = (const float*)d_in[14];
    const float* gamma1 = (const float*)d_in[15];
    const float* beta1  = (const float*)d_in[16];
    const float* gamma2 = (const float*)d_in[17];
    const float* beta2  = (const float*)d_in[18];
    float* out = (float*)d_out;

    float* ws = (float*)d_ws;
    size_t off = 0;
    bfu* Wp1 = (bfu*)(ws + off); off += 18432;               // 36864 bf16
    bfu* Wp2 = (bfu*)(ws + off); off += 18432;
    bfu* Wp3 = (bfu*)(ws + off); off += 9216;                // 18432 bf16
    float* stats = ws + off; off += 128;
    float* sc = ws + off; off += 128;
    float* cnt = ws + off; off += (size_t)NN * RR;
    float* y  = ws + off; off += (size_t)NN * 64;
    bfu* xb   = (bfu*)(ws + off); off += (size_t)NN * 32;    // N*64 bf16
    bfu* h1b  = (bfu*)(ws + off); off += (size_t)NN * 32;
    bfu* hb   = (bfu*)(ws + off); off += (size_t)NN * 32;
    int* offs = (int*)(ws + off); off += NN + 4;
    int* fill = (int*)(ws + off); off += NN;
    int* bsum = (int*)(ws + off); off += 256;
    unsigned* esrt = (unsigned*)(ws + off); off += NE;

    // ---- once: packed weights + bf16 x + counts + CSR ----
    build_w_packed<<<dim3((576 * 64 + 255) / 256), dim3(256), 0, stream>>>(comp1, bases1, root1, Wp1, 64);
    build_w_packed<<<dim3((576 * 64 + 255) / 256), dim3(256), 0, stream>>>(comp2, bases2, root2, Wp2, 64);
    build_w_packed<<<dim3((576 * 32 + 255) / 256), dim3(256), 0, stream>>>(comp3, bases3, root3, Wp3, 32);
    cvt_bf16<<<dim3(512), dim3(256), 0, stream>>>(x, xb, (long)NN * 64);
    zero_f32<<<dim3(512), dim3(256), 0, stream>>>(cnt, (long)NN * RR);
    zero_f32<<<dim3(128), dim3(256), 0, stream>>>((float*)fill, NN);
    edge_count<<<dim3(1024), dim3(256), 0, stream>>>(ei, et, cnt);
    scan1<<<dim3(SCAN_B), dim3(256), 0, stream>>>(cnt, offs, bsum);
    scan2<<<dim3(1), dim3(64), 0, stream>>>(bsum, offs);
    scan3<<<dim3(SCAN_B), dim3(256), 0, stream>>>(offs, bsum);
    place<<<dim3(1024), dim3(256), 0, stream>>>(ei, et, offs, fill, esrt);

    // ---- layer 1 ----
    agg_gemm<64, true><<<dim3(NN / 16), dim3(256), 0, stream>>>(offs, esrt, cnt, xb, Wp1, bias1, y);
    zero_f32<<<dim3(1), dim3(128), 0, stream>>>(stats, 128);
    bn_stats<<<dim3(256), dim3(256), 0, stream>>>(y, stats);
    bn_finalize<<<dim3(1), dim3(64), 0, stream>>>(stats, gamma1, beta1, sc);
    bn_apply<<<dim3(1024), dim3(256), 0, stream>>>(y, sc, nullptr, h1b);

    // ---- layer 2 ----
    agg_gemm<64, true><<<dim3(NN / 16), dim3(256), 0, stream>>>(offs, esrt, cnt, h1b, Wp2, bias2, y);
    zero_f32<<<dim3(1), dim3(128), 0, stream>>>(stats, 128);
    bn_stats<<<dim3(256), dim3(256), 0, stream>>>(y, stats);
    bn_finalize<<<dim3(1), dim3(64), 0, stream>>>(stats, gamma2, beta2, sc);
    bn_apply<<<dim3(1024), dim3(256), 0, stream>>>(y, sc, h1b, hb);

    // ---- layer 3 (output) ----
    agg_gemm<32, false><<<dim3(NN / 16), dim3(256), 0, stream>>>(offs, esrt, cnt, hb, Wp3, bias3, out);
}

// Round 8
// 290.937 us; speedup vs baseline: 4.2338x; 1.1878x over previous
//
#include <hip/hip_runtime.h>

#define NN 50000
#define NE 800000
#define RR 8
#define BB 8
#define EPSV 1e-5f
#define SCAN_B ((NN + 255) / 256)   // 196
#define NGRP 64

typedef unsigned short bfu;
typedef __attribute__((ext_vector_type(8))) short bf16x8;
typedef __attribute__((ext_vector_type(4))) float f32x4;

__device__ inline float bf2f(bfu u) { return __uint_as_float(((unsigned)u) << 16); }
__device__ inline bfu f2bf(float f) {
    unsigned u = __float_as_uint(f);
    return (bfu)((u + 0x7fffu + ((u >> 16) & 1u)) >> 16);   // RTNE
}

#define NW1 36864L
#define NW2 36864L
#define NW3 18432L
#define NCV ((long)NN * 64)
#define NZ  (400000L + 50000L + 2L * NGRP * 128)

// ---------------- W packing: logical W[k][o] -> MFMA B-frag layout ----------------
__device__ inline void build_one(const float* __restrict__ comp, const float* __restrict__ bases,
                                 const float* __restrict__ root, bfu* __restrict__ Wp,
                                 int O, int idx) {
    int k = idx / O, o = idx % O;
    float val;
    if (k < 512) {
        int r = k >> 6, i = k & 63;
        val = 0.f;
#pragma unroll
        for (int b = 0; b < BB; ++b)
            val += comp[r * BB + b] * bases[(b * 64 + i) * O + o];
    } else {
        val = root[(k - 512) * O + o];
    }
    int kt = k >> 5, kk = k & 31;
    int lane = ((kk >> 3) << 4) | (o & 15);
    int pos = ((kt * (O / 16) + (o >> 4)) * 64 + lane) * 8 + (kk & 7);
    Wp[pos] = f2bf(val);
}

// ---------------- once: W builds + x->bf16 + zero (cnt|fill|stats1|stats2) ----------------
__global__ void prep(const float* __restrict__ c1, const float* __restrict__ b1,
                     const float* __restrict__ r1, bfu* __restrict__ Wp1,
                     const float* __restrict__ c2, const float* __restrict__ b2,
                     const float* __restrict__ r2, bfu* __restrict__ Wp2,
                     const float* __restrict__ c3, const float* __restrict__ b3,
                     const float* __restrict__ r3, bfu* __restrict__ Wp3,
                     const float* __restrict__ x, bfu* __restrict__ xb,
                     float* __restrict__ zbase) {
    long i = (long)blockIdx.x * blockDim.x + threadIdx.x;
    long stride = (long)gridDim.x * blockDim.x;
    const long tot = NW1 + NW2 + NW3 + NCV + NZ;
    for (; i < tot; i += stride) {
        if (i < NW1) build_one(c1, b1, r1, Wp1, 64, (int)i);
        else if (i < NW1 + NW2) build_one(c2, b2, r2, Wp2, 64, (int)(i - NW1));
        else if (i < NW1 + NW2 + NW3) build_one(c3, b3, r3, Wp3, 32, (int)(i - NW1 - NW2));
        else if (i < NW1 + NW2 + NW3 + NCV) { long k = i - NW1 - NW2 - NW3; xb[k] = f2bf(x[k]); }
        else zbase[i - (NW1 + NW2 + NW3 + NCV)] = 0.f;
    }
}

// ---------------- once: per-(dst,rel) counts, range-binned (writes stay L2-local) ----------------
__global__ void edge_count(const int* __restrict__ ei, const int* __restrict__ et,
                           float* __restrict__ cnt) {
    int range = blockIdx.x >> 8;
    int lo = range * (NN / 8), hi = lo + NN / 8;
    int i = (blockIdx.x & 255) * 256 + threadIdx.x;
    for (int e = i; e < NE; e += 256 * 256) {
        int d = ei[NE + e];
        if (d >= lo && d < hi)
            atomicAdd(&cnt[(size_t)d * RR + et[e]], 1.0f);
    }
}

// ---------------- once: exclusive scan of degree (= row-sum of cnt) -> offs ----------------
__global__ void scan1(const float* __restrict__ cnt, int* __restrict__ offs, int* __restrict__ bsum) {
    __shared__ int sh[256];
    int b = blockIdx.x, t = threadIdx.x;
    int i = b * 256 + t;
    int v = 0;
    if (i < NN) {
        float s = 0.f;
#pragma unroll
        for (int r = 0; r < RR; ++r) s += cnt[(size_t)i * RR + r];
        v = (int)s;
    }
    sh[t] = v;
    __syncthreads();
    for (int s = 1; s < 256; s <<= 1) {
        int tmp = (t >= s) ? sh[t - s] : 0;
        __syncthreads();
        sh[t] += tmp;
        __syncthreads();
    }
    if (i < NN) offs[i] = sh[t] - v;
    if (t == 255) bsum[b] = sh[255];
}

__global__ void scan2(int* __restrict__ bsum, int* __restrict__ offs) {
    if (threadIdx.x == 0 && blockIdx.x == 0) {
        int run = 0;
        for (int b = 0; b < SCAN_B; ++b) { int t = bsum[b]; bsum[b] = run; run += t; }
        offs[NN] = run;
    }
}

__global__ void scan3(int* __restrict__ offs, const int* __restrict__ bsum) {
    int b = blockIdx.x, t = threadIdx.x;
    int i = b * 256 + t;
    if (i < NN) offs[i] += bsum[b];
}

// ---------------- once: place edges dst-sorted, range-binned ----------------
__global__ void place(const int* __restrict__ ei, const int* __restrict__ et,
                      const int* __restrict__ offs, int* __restrict__ fill,
                      unsigned* __restrict__ esrt) {
    int range = blockIdx.x >> 8;
    int lo = range * (NN / 8), hi = lo + NN / 8;
    int i = (blockIdx.x & 255) * 256 + threadIdx.x;
    for (int e = i; e < NE; e += 256 * 256) {
        int d = ei[NE + e];
        if (d >= lo && d < hi) {
            int pos = offs[d] + atomicAdd(&fill[d], 1);
            esrt[pos] = ((unsigned)ei[e] << 3) | (unsigned)et[e];
        }
    }
}

// ---------------- fused per layer: aggregate -> LDS A-frags -> MFMA GEMM (+BN stats) ----------------
#define ACCUMS(SU, V)                          \
    switch ((SU) & 7) {                        \
        case 0: a0 += (V); break;              \
        case 1: a1 += (V); break;              \
        case 2: a2 += (V); break;              \
        case 3: a3 += (V); break;              \
        case 4: a4 += (V); break;              \
        case 5: a5 += (V); break;              \
        case 6: a6 += (V); break;              \
        default: a7 += (V); break;             \
    }
#define RFL(X) __builtin_amdgcn_readfirstlane((int)(X))
#define GATH(S) bf2f(xb[((size_t)((unsigned)(S) >> 3)) * 64 + lane])

template <int O, bool RELU, bool STATS>
__global__ __launch_bounds__(256) void agg_gemm(const int* __restrict__ offs,
                                                const unsigned* __restrict__ esrt,
                                                const float* __restrict__ cnt,
                                                const bfu* __restrict__ xb,
                                                const bfu* __restrict__ Wp,
                                                const float* __restrict__ bias,
                                                float* __restrict__ outp,
                                                float* __restrict__ stats) {
    constexpr int CT = O / 16;
    __shared__ bfu Af[1152 * 8];                     // 18 k-tiles x 64 lanes x 8 bf16 = 18KB
    int wave = threadIdx.x >> 6, lane = threadIdx.x & 63;
    int n0 = blockIdx.x * 16;
    int c = lane;
    int swz_lo = ((c >> 3) & 3) << 4;

#pragma unroll 1
    for (int i = 0; i < 4; ++i) {
        int row = wave * 4 + i;
        int n = n0 + row;
        int j0 = offs[n], j1 = offs[n + 1];
        float a0 = 0.f, a1 = 0.f, a2 = 0.f, a3 = 0.f, a4 = 0.f, a5 = 0.f, a6 = 0.f, a7 = 0.f;
        int j = j0;
        for (; j + 8 <= j1; j += 8) {                // scalar src -> SGPR-base gathers
            int s0 = RFL(esrt[j + 0]), s1 = RFL(esrt[j + 1]);
            int s2 = RFL(esrt[j + 2]), s3 = RFL(esrt[j + 3]);
            int s4 = RFL(esrt[j + 4]), s5 = RFL(esrt[j + 5]);
            int s6 = RFL(esrt[j + 6]), s7 = RFL(esrt[j + 7]);
            float v0 = GATH(s0), v1 = GATH(s1), v2 = GATH(s2), v3 = GATH(s3);
            float v4 = GATH(s4), v5 = GATH(s5), v6 = GATH(s6), v7 = GATH(s7);
            ACCUMS(s0, v0) ACCUMS(s1, v1) ACCUMS(s2, v2) ACCUMS(s3, v3)
            ACCUMS(s4, v4) ACCUMS(s5, v5) ACCUMS(s6, v6) ACCUMS(s7, v7)
        }
        for (; j + 4 <= j1; j += 4) {
            int s0 = RFL(esrt[j + 0]), s1 = RFL(esrt[j + 1]);
            int s2 = RFL(esrt[j + 2]), s3 = RFL(esrt[j + 3]);
            float v0 = GATH(s0), v1 = GATH(s1), v2 = GATH(s2), v3 = GATH(s3);
            ACCUMS(s0, v0) ACCUMS(s1, v1) ACCUMS(s2, v2) ACCUMS(s3, v3)
        }
        for (; j < j1; ++j) {
            int s0 = RFL(esrt[j]);
            float v0 = GATH(s0);
            ACCUMS(s0, v0)
        }
        // normalize + write A-fragments (granule-XOR-swizzled; verified round 7)
#define WR(r, ar) {                                                            \
        float inv = 1.f / fmaxf(cnt[(size_t)n * RR + (r)], 1.f);               \
        bfu bv = f2bf((ar) * inv);                                             \
        int g = (2 * (r) + (c >> 5)) * 64 + (row | swz_lo);                    \
        int gs = g ^ ((g >> 3) & 7) ^ ((g >> 6) & 7);                          \
        Af[gs * 8 + (c & 7)] = bv; }
        WR(0, a0) WR(1, a1) WR(2, a2) WR(3, a3)
        WR(4, a4) WR(5, a5) WR(6, a6) WR(7, a7)
#undef WR
        {   // root-input columns k=512+c  (kt = 16,17)
            bfu bv = xb[(size_t)n * 64 + lane];
            int g = (16 + (c >> 5)) * 64 + (row | swz_lo);
            int gs = g ^ ((g >> 3) & 7) ^ ((g >> 6) & 7);
            Af[gs * 8 + (c & 7)] = bv;
        }
    }
    __syncthreads();

    int ct = wave;
    if (CT == 4 || ct < CT) {
        f32x4 acc = (f32x4){0.f, 0.f, 0.f, 0.f};
#pragma unroll
        for (int kt = 0; kt < 18; ++kt) {
            int g = kt * 64 + lane;
            int gs = g ^ ((g >> 3) & 7) ^ ((g >> 6) & 7);
            bf16x8 af = *(const bf16x8*)&Af[gs * 8];
            bf16x8 bfv = *(const bf16x8*)&Wp[((size_t)(kt * CT + ct) * 64 + lane) * 8];
            acc = __builtin_amdgcn_mfma_f32_16x16x32_bf16(af, bfv, acc, 0, 0, 0);
        }
        int col = ct * 16 + (lane & 15);
        float b = bias[col];
        float ssum = 0.f, sq = 0.f;
#pragma unroll
        for (int jj = 0; jj < 4; ++jj) {
            int row = (lane >> 4) * 4 + jj;
            float v = acc[jj] + b;
            if (RELU) v = fmaxf(v, 0.f);
            outp[(size_t)(n0 + row) * O + col] = v;
            if (STATS) { ssum += v; sq += v * v; }
        }
        if (STATS) {
            ssum += __shfl_xor(ssum, 16); ssum += __shfl_xor(ssum, 32);
            sq   += __shfl_xor(sq, 16);   sq   += __shfl_xor(sq, 32);
            if ((lane >> 4) == 0) {
                int g = blockIdx.x & (NGRP - 1);
                atomicAdd(&stats[g * 128 + col], ssum);
                atomicAdd(&stats[g * 128 + 64 + col], sq);
            }
        }
    }
}

// ---------------- BN: finalize (redundant per block) + apply, fused ----------------
template <bool HASRES>
__global__ __launch_bounds__(256) void bn_apply(const float* __restrict__ y,
                                                const float* __restrict__ stats,
                                                const float* __restrict__ gamma,
                                                const float* __restrict__ beta,
                                                const bfu* __restrict__ resb,
                                                bfu* __restrict__ hb) {
    __shared__ float sc[128];
    int t = threadIdx.x;
    if (t < 64) {
        float s = 0.f, q = 0.f;
        for (int g = 0; g < NGRP; ++g) {
            s += stats[g * 128 + t];
            q += stats[g * 128 + 64 + t];
        }
        float mu = s / (float)NN;
        float var = q / (float)NN - mu * mu;
        float scale = gamma[t] * rsqrtf(var + EPSV);
        sc[t] = scale;
        sc[64 + t] = beta[t] - mu * scale;
    }
    __syncthreads();
    long tot = (long)NN * 64;
    long stride = (long)gridDim.x * blockDim.x;
    for (long i = (long)blockIdx.x * blockDim.x + threadIdx.x; i < tot; i += stride) {
        int cc = (int)(i & 63);
        float v = y[i] * sc[cc] + sc[64 + cc];
        if (HASRES) v += bf2f(resb[i]);
        hb[i] = f2bf(v);
    }
}

extern "C" void kernel_launch(void* const* d_in, const int* in_sizes, int n_in,
                              void* d_out, int out_size, void* d_ws, size_t ws_size,
                              hipStream_t stream) {
    const float* x      = (const float*)d_in[0];
    const int*   ei     = (const int*)d_in[1];
    const int*   et     = (const int*)d_in[2];
    const float* comp1  = (const float*)d_in[3];
    const float* bases1 = (const float*)d_in[4];
    const float* root1  = (const float*)d_in[5];
    const float* bias1  = (const float*)d_in[6];
    const float* comp2  = (const float*)d_in[7];
    const float* bases2 = (const float*)d_in[8];
    const float* root2  = (const float*)d_in[9];
    const float* bias2  = (const float*)d_in[10];
    const float* bias3  = (const float*)d_in[14];
    const float* comp3  = (const float*)d_in[11];
    const float* bases3 = (const float*)d_in[12];
    const float* root3  = (const float*)d_in[13];
    const float* gamma1 = (const float*)d_in[15];
    const float* beta1  = (const float*)d_in[16];
    const float* gamma2 = (const float*)d_in[17];
    const float* beta2  = (const float*)d_in[18];
    float* out = (float*)d_out;

    float* ws = (float*)d_ws;
    size_t off = 0;
    bfu* Wp1 = (bfu*)(ws + off); off += 18432;                // 36864 bf16
    bfu* Wp2 = (bfu*)(ws + off); off += 18432;
    bfu* Wp3 = (bfu*)(ws + off); off += 9216;                 // 18432 bf16
    float* cnt    = ws + off; off += (size_t)NN * RR;         // 400000   -- zero region start
    int*   fill   = (int*)(ws + off); off += NN;              // 50000
    float* stats1 = ws + off; off += NGRP * 128;              // 8192
    float* stats2 = ws + off; off += NGRP * 128;              // 8192     -- zero region end
    float* y  = ws + off; off += (size_t)NN * 64;
    bfu* xb   = (bfu*)(ws + off); off += (size_t)NN * 32;
    bfu* h1b  = (bfu*)(ws + off); off += (size_t)NN * 32;
    bfu* hb   = (bfu*)(ws + off); off += (size_t)NN * 32;
    int* offs = (int*)(ws + off); off += NN + 4;
    int* bsum = (int*)(ws + off); off += 256;
    unsigned* esrt = (unsigned*)(ws + off); off += NE;

    // ---- once: prep (W pack + bf16 cvt + zeros), counts, CSR ----
    prep<<<dim3(2048), dim3(256), 0, stream>>>(comp1, bases1, root1, Wp1,
                                               comp2, bases2, root2, Wp2,
                                               comp3, bases3, root3, Wp3,
                                               x, xb, cnt);
    edge_count<<<dim3(2048), dim3(256), 0, stream>>>(ei, et, cnt);
    scan1<<<dim3(SCAN_B), dim3(256), 0, stream>>>(cnt, offs, bsum);
    scan2<<<dim3(1), dim3(64), 0, stream>>>(bsum, offs);
    scan3<<<dim3(SCAN_B), dim3(256), 0, stream>>>(offs, bsum);
    place<<<dim3(2048), dim3(256), 0, stream>>>(ei, et, offs, fill, esrt);

    // ---- layer 1 ----
    agg_gemm<64, true, true><<<dim3(NN / 16), dim3(256), 0, stream>>>(offs, esrt, cnt, xb, Wp1, bias1, y, stats1);
    bn_apply<false><<<dim3(256), dim3(256), 0, stream>>>(y, stats1, gamma1, beta1, nullptr, h1b);

    // ---- layer 2 ----
    agg_gemm<64, true, true><<<dim3(NN / 16), dim3(256), 0, stream>>>(offs, esrt, cnt, h1b, Wp2, bias2, y, stats2);
    bn_apply<true><<<dim3(256), dim3(256), 0, stream>>>(y, stats2, gamma2, beta2, h1b, hb);

    // ---- layer 3 (output) ----
    agg_gemm<32, false, false><<<dim3(NN / 16), dim3(256), 0, stream>>>(offs, esrt, cnt, hb, Wp3, bias3, out, nullptr);
}